// Round 6
// baseline (276.311 us; speedup 1.0000x reference)
//
#include <hip/hip_runtime.h>

// TinyNeRF fused MLP, fp16 MFMA 16x16x32, fp32 accum.
// Round-5 (resubmit; round-5 bench was an infra failure, kernel never ran):
// round-4 architecture (ALL weights persistent in LDS, 160 KB, zero
// steady-state barriers, in-register layer chaining via K-permuted weights;
// 512-thr block, 8 waves = 2/SIMD, 1 block/CU) with the register allocator
// pinned: amdgpu_waves_per_eu(2,2) => VGPR cap 256 and NO occupancy-driven
// squeeze to 128 (round 4 spilled ~230 MB/dispatch because the backend
// targeted 4 waves/EU = 128 regs that LDS makes unreachable).
// Also: hold raw dir components (4 regs) through the trunk, build the dir
// encoding fragment only at c1 (-12 long-lived VGPRs).

typedef _Float16 half8 __attribute__((ext_vector_type(8)));
typedef _Float16 half2v __attribute__((ext_vector_type(2)));
typedef float f32x4 __attribute__((ext_vector_type(4)));

typedef __attribute__((address_space(1))) const unsigned int GU32;
typedef __attribute__((address_space(3))) unsigned int LU32;

#define MFMA16(A,B,C) __builtin_amdgcn_mfma_f32_16x16x32_f16(A,B,C,0,0,0)

#define G1A 0
#define G1B 2560
#define G2A 5120
#define G2B 13312
#define G3A 21504
#define G3B 29696
#define G4A 37888
#define G4B 46080
#define FAC 54272
#define FBC 62464
#define C1C 70656
#define C2C 80896
#define IMG_HALVES 81920

// K-axis permutation: B-slot (ks,g,jj) holds output dim
// (2ks + jj>>2)*16 + g*4 + (jj&3) of the previous layer.
__device__ __forceinline__ int permk(int s){
  int ks = s >> 5, gg = (s >> 3) & 3, jj = s & 7;
  return (2*ks + (jj >> 2))*16 + gg*4 + (jj & 3);
}

__global__ void prep(const float* __restrict__ g1w, const float* __restrict__ g2w,
                     const float* __restrict__ g3w, const float* __restrict__ g4w,
                     const float* __restrict__ dw,  const float* __restrict__ fw,
                     const float* __restrict__ c1w, const float* __restrict__ c2w,
                     _Float16* __restrict__ img) {
  int i = blockIdx.x*256 + threadIdx.x;
  if (i >= IMG_HALVES) return;
  float v = 0.f;
  size_t byteoff;
  if (i < G2A) {                       // g1: linear [2][64][40]
    int hf = (i < G1B) ? 0 : 1;
    int r = i - hf*G1B;
    int o = r / 40, s = r % 40;
    v = (s < 36) ? g1w[s*128 + hf*64 + o] : 0.f;
    byteoff = (size_t)i*2;
  } else if (i < C1C) {                // six [64][128] chunks, swz7, permk
    int ci = (i - G2A) >> 13;
    int r  = (i - G2A) & 8191;
    int o = r >> 7, s = r & 127;
    const float* W = (ci < 2) ? g2w : (ci < 4) ? g3w : (ci < 6) ? g4w : fw;
    int obase = (ci & 1)*64;
    v = W[permk(s)*128 + obase + o];
    byteoff = (size_t)(G2A + ci*8192)*2 + o*256 + ((2*s) ^ ((o & 7) << 4));
  } else if (i < C2C) {                // c1 [64][160], swz2
    int r = i - C1C;
    int o = r / 160, s = r % 160;
    if (s < 128)      v = c1w[permk(s)*64 + o];
    else if (s < 152) v = c1w[s*64 + o];
    else if (o < 16)  v = dw[permk(8*o + (s - 152))];   // d_w stash
    else              v = 0.f;
    byteoff = (size_t)C1C*2 + o*320 + ((2*s) ^ ((o & 3) << 4));
  } else {                             // c2 [16][64], swz7
    int r = i - C2C;
    int o = r >> 6, s = r & 63;
    v = (o < 3) ? c2w[permk(s)*3 + o] : 0.f;
    byteoff = (size_t)C2C*2 + o*128 + ((2*s) ^ ((o & 7) << 4));
  }
  *(_Float16*)((char*)img + byteoff) = (_Float16)v;
}

__device__ __forceinline__ half8 mk8(uint2 a, uint2 b){
  union { unsigned int u[4]; half8 h; } x;
  x.u[0]=a.x; x.u[1]=a.y; x.u[2]=b.x; x.u[3]=b.y; return x.h;
}
__device__ __forceinline__ half8 mkh8(float a,float b,float c,float d,
                                      float e,float f,float g,float h){
  half8 r; r[0]=(_Float16)a; r[1]=(_Float16)b; r[2]=(_Float16)c; r[3]=(_Float16)d;
  r[4]=(_Float16)e; r[5]=(_Float16)f; r[6]=(_Float16)g; r[7]=(_Float16)h; return r;
}
__device__ __forceinline__ uint2 pack4(float a0,float a1,float a2,float a3,bool relu){
  if (relu){ a0=fmaxf(a0,0.f); a1=fmaxf(a1,0.f); a2=fmaxf(a2,0.f); a3=fmaxf(a3,0.f); }
  union { _Float16 h[4]; uint2 u; } x;
  x.h[0]=(_Float16)a0; x.h[1]=(_Float16)a1; x.h[2]=(_Float16)a2; x.h[3]=(_Float16)a3;
  return x.u;
}

// one og-half: O=64 (og 0..3) from persistent-LDS chunk at `buf`
template<int KROWB, int KS, int PKB, bool RELU, int SWZM>
__device__ __forceinline__ void chunk64(const _Float16* buf, int lane,
                                        const float* __restrict__ bias,
                                        const half8 (&bf)[4][5], uint2 (&pk)[8][4]) {
  const int g = lane >> 4, n = lane & 15;
  const int swz = (n & SWZM) << 4;
  const char* lb = (const char*)buf + n*KROWB;
#pragma unroll
  for (int og = 0; og < 4; ++og) {
    half8 wf[KS];
#pragma unroll
    for (int ks = 0; ks < KS; ++ks)
      wf[ks] = *(const half8*)(lb + og*16*KROWB + ((ks*64 + g*16) ^ swz));
    f32x4 bv = *(const f32x4*)(bias + og*16 + g*4);
    f32x4 acc[4];
#pragma unroll
    for (int st = 0; st < 4; ++st) acc[st] = bv;
    __builtin_amdgcn_s_setprio(1);
#pragma unroll
    for (int ks = 0; ks < KS; ++ks)
#pragma unroll
      for (int st = 0; st < 4; ++st)
        acc[st] = MFMA16(wf[ks], bf[st][ks], acc[st]);
    __builtin_amdgcn_s_setprio(0);
#pragma unroll
    for (int st = 0; st < 4; ++st)
      pk[PKB+og][st] = pack4(acc[st][0], acc[st][1], acc[st][2], acc[st][3], RELU);
  }
}

#define REB4() do{ \
  _Pragma("unroll") \
  for (int st_ = 0; st_ < 4; ++st_){ \
    half8 n0 = mk8(pk[0][st_], pk[1][st_]); \
    half8 n1 = mk8(pk[2][st_], pk[3][st_]); \
    half8 n2 = mk8(pk[4][st_], pk[5][st_]); \
    half8 n3 = mk8(pk[6][st_], pk[7][st_]); \
    bf[st_][0]=n0; bf[st_][1]=n1; bf[st_][2]=n2; bf[st_][3]=n3; \
  } \
}while(0)

__global__ __attribute__((amdgpu_flat_work_group_size(512, 512),
                          amdgpu_waves_per_eu(2, 2)))
void nerf_fused(
    const float* __restrict__ pos, const float* __restrict__ dirs,
    const _Float16* __restrict__ img,
    const float* __restrict__ b1, const float* __restrict__ b2,
    const float* __restrict__ b3, const float* __restrict__ b4,
    const float* __restrict__ bd, const float* __restrict__ bfl,
    const float* __restrict__ bc1, const float* __restrict__ bc2,
    float* __restrict__ out, int N) {
  __shared__ __align__(16) _Float16 W[IMG_HALVES];   // 160 KB exactly
  const int tid = threadIdx.x, wave = tid >> 6, lane = tid & 63;
  const int g = lane >> 4, n = lane & 15;

  // one-time weight stage: 512 thr x 20 x 16B = 163840 B
#pragma unroll
  for (int r = 0; r < 20; ++r)
    __builtin_amdgcn_global_load_lds((GU32*)((const char*)img + tid*16 + (size_t)r*8192),
                                     (LU32*)((char*)&W[0] + tid*16 + r*8192), 16, 0, 0);
  __syncthreads();   // the only barrier

  half8 bf[4][5];
  uint2 pk[8][4];
  float dv[4];                 // raw per-lane dir component (dim g), 4 regs
  const float PI = 3.14159265358979f;
  half8 z = {};

  for (int it = 0; it < 8; ++it) {
    const int pbase = blockIdx.x*4096 + wave*512 + it*64;

    // ---- encode positions directly into B-fragment form ----
#pragma unroll
    for (int st = 0; st < 4; ++st) {
      int p = pbase + st*16 + n;
      float S[3][6], C[3][6];
      const float* pp = pos + (size_t)p*3;
#pragma unroll
      for (int d = 0; d < 3; ++d) {
        float x = pp[d]*PI;
        float s = __sinf(x), c = __cosf(x);
        S[d][0]=s; C[d][0]=c;
#pragma unroll
        for (int l = 1; l < 6; ++l) {
          float s2 = 2.f*s*c, c2 = c*c - s*s;
          S[d][l]=s2; C[d][l]=c2; s=s2; c=c2;
        }
      }
      half8 e0, e1 = z;
      if (g == 0) {
        e0 = mkh8(S[0][0],S[0][1],S[0][2],S[0][3],S[0][4],S[0][5],C[0][0],C[0][1]);
        e1 = mkh8(C[2][2],C[2][3],C[2][4],C[2][5],0.f,0.f,0.f,0.f);
      } else if (g == 1) {
        e0 = mkh8(C[0][2],C[0][3],C[0][4],C[0][5],S[1][0],S[1][1],S[1][2],S[1][3]);
      } else if (g == 2) {
        e0 = mkh8(S[1][4],S[1][5],C[1][0],C[1][1],C[1][2],C[1][3],C[1][4],C[1][5]);
      } else {
        e0 = mkh8(S[2][0],S[2][1],S[2][2],S[2][3],S[2][4],S[2][5],C[2][0],C[2][1]);
      }
      bf[st][0]=e0; bf[st][1]=e1;
      // raw dir component only; encode ladder deferred to c1
      dv[st] = (g < 3) ? dirs[(size_t)p*3 + g] : 0.f;
    }

    // ---- MLP trunk, all weights LDS-resident, no barriers ----
    chunk64< 80,2,0,true ,0>(&W[G1A], lane, b1,     bf, pk);
    chunk64< 80,2,4,true ,0>(&W[G1B], lane, b1+64,  bf, pk);
    REB4();
    chunk64<256,4,0,true ,7>(&W[G2A], lane, b2,     bf, pk);
    chunk64<256,4,4,true ,7>(&W[G2B], lane, b2+64,  bf, pk);
    REB4();
    chunk64<256,4,0,true ,7>(&W[G3A], lane, b3,     bf, pk);
    chunk64<256,4,4,true ,7>(&W[G3B], lane, b3+64,  bf, pk);
    REB4();
    chunk64<256,4,0,true ,7>(&W[G4A], lane, b4,     bf, pk);
    chunk64<256,4,4,true ,7>(&W[G4B], lane, b4+64,  bf, pk);
    REB4();   // bf = geo_feat fragments

    // ---- density head: dot with d_w stash (c1 pad cols), wave-local ----
    {
      half8 dwv[4];
#pragma unroll
      for (int ks = 0; ks < 4; ++ks) {
        int o = ks*4 + g;
        dwv[ks] = *(const half8*)((const char*)&W[C1C] + o*320 + (304 ^ ((o & 3) << 4)));
      }
      float dsum[4];
#pragma unroll
      for (int st = 0; st < 4; ++st) {
        float a = 0.f;
#pragma unroll
        for (int ks = 0; ks < 4; ++ks)
#pragma unroll
          for (int q = 0; q < 4; ++q) {
#if __has_builtin(__builtin_amdgcn_fdot2)
            half2v xv = {bf[st][ks][2*q], bf[st][ks][2*q+1]};
            half2v wv = {dwv[ks][2*q],    dwv[ks][2*q+1]};
            a = __builtin_amdgcn_fdot2(xv, wv, a, false);
#else
            a += (float)bf[st][ks][2*q]   * (float)dwv[ks][2*q];
            a += (float)bf[st][ks][2*q+1] * (float)dwv[ks][2*q+1];
#endif
          }
        a += __shfl_xor(a, 16);
        a += __shfl_xor(a, 32);
        dsum[st] = a;
      }
      if (g == 0) {
        float d0 = bd[0];
#pragma unroll
        for (int st = 0; st < 4; ++st) {
          float x = dsum[st] + d0;
          out[(size_t)3*N + pbase + st*16 + n] = fmaxf(x,0.f) + log1pf(__expf(-fabsf(x)));
        }
      }
    }

    chunk64<256,4,0,false,7>(&W[FAC], lane, bfl,    bf, pk);
    chunk64<256,4,4,false,7>(&W[FBC], lane, bfl+64, bf, pk);
    REB4();   // bf = feature fragments

    // dir encoding, built now from the raw component (freed 12 regs of
    // trunk-long-lived state vs holding the fragment)
#pragma unroll
    for (int st = 0; st < 4; ++st) {
      float xx = dv[st]*PI;
      float s1 = __sinf(xx), c1 = __cosf(xx);
      float sa[4], ca[4]; sa[0]=s1; ca[0]=c1;
#pragma unroll
      for (int l = 1; l < 4; ++l) {
        float s2 = 2.f*s1*c1, c2 = c1*c1 - s1*s1;
        sa[l]=s2; ca[l]=c2; s1=s2; c1=c2;
      }
      bf[st][4] = (g < 3) ? mkh8(sa[0],sa[1],sa[2],sa[3],ca[0],ca[1],ca[2],ca[3]) : z;
    }

    chunk64<320,5,0,true ,3>(&W[C1C], lane, bc1,    bf, pk);
    // c2 input (64 dims -> 2 k-steps)
#pragma unroll
    for (int st = 0; st < 4; ++st) {
      bf[st][0] = mk8(pk[0][st], pk[1][st]);
      bf[st][1] = mk8(pk[2][st], pk[3][st]);
    }

    // ---- rgb head ----
    {
      const char* lb = (const char*)&W[C2C] + n*128;
      const int swz = (n & 7) << 4;
      half8 wf[2];
#pragma unroll
      for (int ks = 0; ks < 2; ++ks)
        wf[ks] = *(const half8*)(lb + ((ks*64 + g*16) ^ swz));
      f32x4 a[4];
#pragma unroll
      for (int st = 0; st < 4; ++st) a[st] = f32x4{0.f,0.f,0.f,0.f};
      __builtin_amdgcn_s_setprio(1);
#pragma unroll
      for (int ks = 0; ks < 2; ++ks)
#pragma unroll
        for (int st = 0; st < 4; ++st) a[st] = MFMA16(wf[ks], bf[st][ks], a[st]);
      __builtin_amdgcn_s_setprio(0);
      if (g == 0) {
        float c0 = bc2[0], c1v = bc2[1], c2v = bc2[2];
#pragma unroll
        for (int st = 0; st < 4; ++st) {
          size_t p = (size_t)(pbase + st*16 + n);
          out[p*3+0] = 1.f/(1.f + __expf(-(a[st][0] + c0)));
          out[p*3+1] = 1.f/(1.f + __expf(-(a[st][1] + c1v)));
          out[p*3+2] = 1.f/(1.f + __expf(-(a[st][2] + c2v)));
        }
      }
    }
  }
}

extern "C" void kernel_launch(void* const* d_in, const int* in_sizes, int n_in,
                              void* d_out, int out_size, void* d_ws, size_t ws_size,
                              hipStream_t stream) {
  const float* pos = (const float*)d_in[0];
  const float* dirs = (const float*)d_in[1];
  const float* g1w = (const float*)d_in[2];
  const float* g1b = (const float*)d_in[3];
  const float* g2w = (const float*)d_in[4];
  const float* g2b = (const float*)d_in[5];
  const float* g3w = (const float*)d_in[6];
  const float* g3b = (const float*)d_in[7];
  const float* g4w = (const float*)d_in[8];
  const float* g4b = (const float*)d_in[9];
  const float* dw  = (const float*)d_in[10];
  const float* db  = (const float*)d_in[11];
  const float* fw  = (const float*)d_in[12];
  const float* fb  = (const float*)d_in[13];
  const float* c1w = (const float*)d_in[14];
  const float* c1b = (const float*)d_in[15];
  const float* c2w = (const float*)d_in[16];
  const float* c2b = (const float*)d_in[17];

  int N = in_sizes[0] / 3;   // 1048576
  _Float16* img = (_Float16*)d_ws;

  prep<<<(IMG_HALVES + 255)/256, 256, 0, stream>>>(
      g1w, g2w, g3w, g4w, dw, fw, c1w, c2w, img);

  // 1 block/CU (160KB LDS), 8 waves (2/SIMD), 8 batches of 64 pts per wave
  nerf_fused<<<N/4096, 512, 0, stream>>>(
      pos, dirs, img, g1b, g2b, g3b, g4b, db, fb, c1b, c2b,
      (float*)d_out, N);
}

// Round 7
// 275.250 us; speedup vs baseline: 1.0039x; 1.0039x over previous
//
#include <hip/hip_runtime.h>

// TinyNeRF fused MLP, fp16 MFMA 16x16x32, fp32 accum.
// Round-7: round-6 structure (ALL weights persistent in LDS, 160 KB, zero
// thread barriers after stage, in-register layer chaining via K-permuted
// weights; 512-thr block, 8 waves = 2/SIMD, 1 block/CU) + the spill fix:
// __builtin_amdgcn_sched_barrier(0) between chunks. Evidence: round 2 (same
// register state, __syncthreads between chunks) = 108 VGPR no spill; rounds
// 4/6 (no fences) = 128 VGPR + ~300 MB scratch reads. The scheduler hoists
// next-chunk ds_reads across chunk boundaries and balloons liveness; the
// compile-time fence restores per-chunk scheduling without any runtime sync.

typedef _Float16 half8 __attribute__((ext_vector_type(8)));
typedef _Float16 half2v __attribute__((ext_vector_type(2)));
typedef float f32x4 __attribute__((ext_vector_type(4)));

typedef __attribute__((address_space(1))) const unsigned int GU32;
typedef __attribute__((address_space(3))) unsigned int LU32;

#define MFMA16(A,B,C) __builtin_amdgcn_mfma_f32_16x16x32_f16(A,B,C,0,0,0)
#define SB() __builtin_amdgcn_sched_barrier(0)

#define G1A 0
#define G1B 2560
#define G2A 5120
#define G2B 13312
#define G3A 21504
#define G3B 29696
#define G4A 37888
#define G4B 46080
#define FAC 54272
#define FBC 62464
#define C1C 70656
#define C2C 80896
#define IMG_HALVES 81920

// K-axis permutation: B-slot (ks,g,jj) holds output dim
// (2ks + jj>>2)*16 + g*4 + (jj&3) of the previous layer.
__device__ __forceinline__ int permk(int s){
  int ks = s >> 5, gg = (s >> 3) & 3, jj = s & 7;
  return (2*ks + (jj >> 2))*16 + gg*4 + (jj & 3);
}

__global__ void prep(const float* __restrict__ g1w, const float* __restrict__ g2w,
                     const float* __restrict__ g3w, const float* __restrict__ g4w,
                     const float* __restrict__ dw,  const float* __restrict__ fw,
                     const float* __restrict__ c1w, const float* __restrict__ c2w,
                     _Float16* __restrict__ img) {
  int i = blockIdx.x*256 + threadIdx.x;
  if (i >= IMG_HALVES) return;
  float v = 0.f;
  size_t byteoff;
  if (i < G2A) {                       // g1: linear [2][64][40]
    int hf = (i < G1B) ? 0 : 1;
    int r = i - hf*G1B;
    int o = r / 40, s = r % 40;
    v = (s < 36) ? g1w[s*128 + hf*64 + o] : 0.f;
    byteoff = (size_t)i*2;
  } else if (i < C1C) {                // six [64][128] chunks, swz7, permk
    int ci = (i - G2A) >> 13;
    int r  = (i - G2A) & 8191;
    int o = r >> 7, s = r & 127;
    const float* W = (ci < 2) ? g2w : (ci < 4) ? g3w : (ci < 6) ? g4w : fw;
    int obase = (ci & 1)*64;
    v = W[permk(s)*128 + obase + o];
    byteoff = (size_t)(G2A + ci*8192)*2 + o*256 + ((2*s) ^ ((o & 7) << 4));
  } else if (i < C2C) {                // c1 [64][160], swz2
    int r = i - C1C;
    int o = r / 160, s = r % 160;
    if (s < 128)      v = c1w[permk(s)*64 + o];
    else if (s < 152) v = c1w[s*64 + o];
    else if (o < 16)  v = dw[permk(8*o + (s - 152))];   // d_w stash
    else              v = 0.f;
    byteoff = (size_t)C1C*2 + o*320 + ((2*s) ^ ((o & 3) << 4));
  } else {                             // c2 [16][64], swz7
    int r = i - C2C;
    int o = r >> 6, s = r & 63;
    v = (o < 3) ? c2w[permk(s)*3 + o] : 0.f;
    byteoff = (size_t)C2C*2 + o*128 + ((2*s) ^ ((o & 7) << 4));
  }
  *(_Float16*)((char*)img + byteoff) = (_Float16)v;
}

__device__ __forceinline__ half8 mk8(uint2 a, uint2 b){
  union { unsigned int u[4]; half8 h; } x;
  x.u[0]=a.x; x.u[1]=a.y; x.u[2]=b.x; x.u[3]=b.y; return x.h;
}
__device__ __forceinline__ half8 mkh8(float a,float b,float c,float d,
                                      float e,float f,float g,float h){
  half8 r; r[0]=(_Float16)a; r[1]=(_Float16)b; r[2]=(_Float16)c; r[3]=(_Float16)d;
  r[4]=(_Float16)e; r[5]=(_Float16)f; r[6]=(_Float16)g; r[7]=(_Float16)h; return r;
}
__device__ __forceinline__ uint2 pack4(float a0,float a1,float a2,float a3,bool relu){
  if (relu){ a0=fmaxf(a0,0.f); a1=fmaxf(a1,0.f); a2=fmaxf(a2,0.f); a3=fmaxf(a3,0.f); }
  union { _Float16 h[4]; uint2 u; } x;
  x.h[0]=(_Float16)a0; x.h[1]=(_Float16)a1; x.h[2]=(_Float16)a2; x.h[3]=(_Float16)a3;
  return x.u;
}

// one og-half: O=64 (og 0..3) from persistent-LDS chunk at `buf`
template<int KROWB, int KS, int PKB, bool RELU, int SWZM>
__device__ __forceinline__ void chunk64(const _Float16* buf, int lane,
                                        const float* __restrict__ bias,
                                        const half8 (&bf)[4][5], uint2 (&pk)[8][4]) {
  const int g = lane >> 4, n = lane & 15;
  const int swz = (n & SWZM) << 4;
  const char* lb = (const char*)buf + n*KROWB;
#pragma unroll
  for (int og = 0; og < 4; ++og) {
    half8 wf[KS];
#pragma unroll
    for (int ks = 0; ks < KS; ++ks)
      wf[ks] = *(const half8*)(lb + og*16*KROWB + ((ks*64 + g*16) ^ swz));
    f32x4 bv = *(const f32x4*)(bias + og*16 + g*4);
    f32x4 acc[4];
#pragma unroll
    for (int st = 0; st < 4; ++st) acc[st] = bv;
    __builtin_amdgcn_s_setprio(1);
#pragma unroll
    for (int ks = 0; ks < KS; ++ks)
#pragma unroll
      for (int st = 0; st < 4; ++st)
        acc[st] = MFMA16(wf[ks], bf[st][ks], acc[st]);
    __builtin_amdgcn_s_setprio(0);
#pragma unroll
    for (int st = 0; st < 4; ++st)
      pk[PKB+og][st] = pack4(acc[st][0], acc[st][1], acc[st][2], acc[st][3], RELU);
  }
}

#define REB4() do{ \
  _Pragma("unroll") \
  for (int st_ = 0; st_ < 4; ++st_){ \
    half8 n0 = mk8(pk[0][st_], pk[1][st_]); \
    half8 n1 = mk8(pk[2][st_], pk[3][st_]); \
    half8 n2 = mk8(pk[4][st_], pk[5][st_]); \
    half8 n3 = mk8(pk[6][st_], pk[7][st_]); \
    bf[st_][0]=n0; bf[st_][1]=n1; bf[st_][2]=n2; bf[st_][3]=n3; \
  } \
}while(0)

__global__ __attribute__((amdgpu_flat_work_group_size(512, 512),
                          amdgpu_waves_per_eu(2, 2)))
void nerf_fused(
    const float* __restrict__ pos, const float* __restrict__ dirs,
    const _Float16* __restrict__ img,
    const float* __restrict__ b1, const float* __restrict__ b2,
    const float* __restrict__ b3, const float* __restrict__ b4,
    const float* __restrict__ bd, const float* __restrict__ bfl,
    const float* __restrict__ bc1, const float* __restrict__ bc2,
    float* __restrict__ out, int N) {
  __shared__ __align__(16) _Float16 W[IMG_HALVES];   // 160 KB exactly
  const int tid = threadIdx.x, wave = tid >> 6, lane = tid & 63;
  const int g = lane >> 4, n = lane & 15;

  // one-time weight stage: 512 thr x 20 x 16B = 163840 B
#pragma unroll
  for (int r = 0; r < 20; ++r)
    __builtin_amdgcn_global_load_lds((GU32*)((const char*)img + tid*16 + (size_t)r*8192),
                                     (LU32*)((char*)&W[0] + tid*16 + r*8192), 16, 0, 0);
  __syncthreads();   // the only thread barrier

  half8 bf[4][5];
  uint2 pk[8][4];
  float dv[4];                 // raw per-lane dir component (dim g), 4 regs
  const float PI = 3.14159265358979f;
  half8 z = {};

#pragma clang loop unroll(disable)
  for (int it = 0; it < 8; ++it) {
    const int pbase = blockIdx.x*4096 + wave*512 + it*64;

    // ---- encode positions directly into B-fragment form ----
#pragma unroll
    for (int st = 0; st < 4; ++st) {
      int p = pbase + st*16 + n;
      float S[3][6], C[3][6];
      const float* pp = pos + (size_t)p*3;
#pragma unroll
      for (int d = 0; d < 3; ++d) {
        float x = pp[d]*PI;
        float s = __sinf(x), c = __cosf(x);
        S[d][0]=s; C[d][0]=c;
#pragma unroll
        for (int l = 1; l < 6; ++l) {
          float s2 = 2.f*s*c, c2 = c*c - s*s;
          S[d][l]=s2; C[d][l]=c2; s=s2; c=c2;
        }
      }
      half8 e0, e1 = z;
      if (g == 0) {
        e0 = mkh8(S[0][0],S[0][1],S[0][2],S[0][3],S[0][4],S[0][5],C[0][0],C[0][1]);
        e1 = mkh8(C[2][2],C[2][3],C[2][4],C[2][5],0.f,0.f,0.f,0.f);
      } else if (g == 1) {
        e0 = mkh8(C[0][2],C[0][3],C[0][4],C[0][5],S[1][0],S[1][1],S[1][2],S[1][3]);
      } else if (g == 2) {
        e0 = mkh8(S[1][4],S[1][5],C[1][0],C[1][1],C[1][2],C[1][3],C[1][4],C[1][5]);
      } else {
        e0 = mkh8(S[2][0],S[2][1],S[2][2],S[2][3],S[2][4],S[2][5],C[2][0],C[2][1]);
      }
      bf[st][0]=e0; bf[st][1]=e1;
      // raw dir component only; encode ladder deferred to c1
      dv[st] = (g < 3) ? dirs[(size_t)p*3 + g] : 0.f;
    }
    SB();

    // ---- MLP trunk, weights LDS-resident; sched fences bound liveness ----
    chunk64< 80,2,0,true ,0>(&W[G1A], lane, b1,     bf, pk); SB();
    chunk64< 80,2,4,true ,0>(&W[G1B], lane, b1+64,  bf, pk); SB();
    REB4(); SB();
    chunk64<256,4,0,true ,7>(&W[G2A], lane, b2,     bf, pk); SB();
    chunk64<256,4,4,true ,7>(&W[G2B], lane, b2+64,  bf, pk); SB();
    REB4(); SB();
    chunk64<256,4,0,true ,7>(&W[G3A], lane, b3,     bf, pk); SB();
    chunk64<256,4,4,true ,7>(&W[G3B], lane, b3+64,  bf, pk); SB();
    REB4(); SB();
    chunk64<256,4,0,true ,7>(&W[G4A], lane, b4,     bf, pk); SB();
    chunk64<256,4,4,true ,7>(&W[G4B], lane, b4+64,  bf, pk); SB();
    REB4(); SB();   // bf = geo_feat fragments

    // ---- density head: dot with d_w stash (c1 pad cols), wave-local ----
    {
      half8 dwv[4];
#pragma unroll
      for (int ks = 0; ks < 4; ++ks) {
        int o = ks*4 + g;
        dwv[ks] = *(const half8*)((const char*)&W[C1C] + o*320 + (304 ^ ((o & 3) << 4)));
      }
      float dsum[4];
#pragma unroll
      for (int st = 0; st < 4; ++st) {
        float a = 0.f;
#pragma unroll
        for (int ks = 0; ks < 4; ++ks)
#pragma unroll
          for (int q = 0; q < 4; ++q) {
#if __has_builtin(__builtin_amdgcn_fdot2)
            half2v xv = {bf[st][ks][2*q], bf[st][ks][2*q+1]};
            half2v wv = {dwv[ks][2*q],    dwv[ks][2*q+1]};
            a = __builtin_amdgcn_fdot2(xv, wv, a, false);
#else
            a += (float)bf[st][ks][2*q]   * (float)dwv[ks][2*q];
            a += (float)bf[st][ks][2*q+1] * (float)dwv[ks][2*q+1];
#endif
          }
        a += __shfl_xor(a, 16);
        a += __shfl_xor(a, 32);
        dsum[st] = a;
      }
      if (g == 0) {
        float d0 = bd[0];
#pragma unroll
        for (int st = 0; st < 4; ++st) {
          float x = dsum[st] + d0;
          out[(size_t)3*N + pbase + st*16 + n] = fmaxf(x,0.f) + log1pf(__expf(-fabsf(x)));
        }
      }
    }
    SB();

    chunk64<256,4,0,false,7>(&W[FAC], lane, bfl,    bf, pk); SB();
    chunk64<256,4,4,false,7>(&W[FBC], lane, bfl+64, bf, pk); SB();
    REB4(); SB();   // bf = feature fragments

    // dir encoding, built now from the raw component
#pragma unroll
    for (int st = 0; st < 4; ++st) {
      float xx = dv[st]*PI;
      float s1 = __sinf(xx), c1 = __cosf(xx);
      float sa[4], ca[4]; sa[0]=s1; ca[0]=c1;
#pragma unroll
      for (int l = 1; l < 4; ++l) {
        float s2 = 2.f*s1*c1, c2 = c1*c1 - s1*s1;
        sa[l]=s2; ca[l]=c2; s1=s2; c1=c2;
      }
      bf[st][4] = (g < 3) ? mkh8(sa[0],sa[1],sa[2],sa[3],ca[0],ca[1],ca[2],ca[3]) : z;
    }
    SB();

    chunk64<320,5,0,true ,3>(&W[C1C], lane, bc1,    bf, pk); SB();
    // c2 input (64 dims -> 2 k-steps)
#pragma unroll
    for (int st = 0; st < 4; ++st) {
      bf[st][0] = mk8(pk[0][st], pk[1][st]);
      bf[st][1] = mk8(pk[2][st], pk[3][st]);
    }
    SB();

    // ---- rgb head ----
    {
      const char* lb = (const char*)&W[C2C] + n*128;
      const int swz = (n & 7) << 4;
      half8 wf[2];
#pragma unroll
      for (int ks = 0; ks < 2; ++ks)
        wf[ks] = *(const half8*)(lb + ((ks*64 + g*16) ^ swz));
      f32x4 a[4];
#pragma unroll
      for (int st = 0; st < 4; ++st) a[st] = f32x4{0.f,0.f,0.f,0.f};
      __builtin_amdgcn_s_setprio(1);
#pragma unroll
      for (int ks = 0; ks < 2; ++ks)
#pragma unroll
        for (int st = 0; st < 4; ++st) a[st] = MFMA16(wf[ks], bf[st][ks], a[st]);
      __builtin_amdgcn_s_setprio(0);
      if (g == 0) {
        float c0 = bc2[0], c1v = bc2[1], c2v = bc2[2];
#pragma unroll
        for (int st = 0; st < 4; ++st) {
          size_t p = (size_t)(pbase + st*16 + n);
          out[p*3+0] = 1.f/(1.f + __expf(-(a[st][0] + c0)));
          out[p*3+1] = 1.f/(1.f + __expf(-(a[st][1] + c1v)));
          out[p*3+2] = 1.f/(1.f + __expf(-(a[st][2] + c2v)));
        }
      }
    }
    SB();
  }
}

extern "C" void kernel_launch(void* const* d_in, const int* in_sizes, int n_in,
                              void* d_out, int out_size, void* d_ws, size_t ws_size,
                              hipStream_t stream) {
  const float* pos = (const float*)d_in[0];
  const float* dirs = (const float*)d_in[1];
  const float* g1w = (const float*)d_in[2];
  const float* g1b = (const float*)d_in[3];
  const float* g2w = (const float*)d_in[4];
  const float* g2b = (const float*)d_in[5];
  const float* g3w = (const float*)d_in[6];
  const float* g3b = (const float*)d_in[7];
  const float* g4w = (const float*)d_in[8];
  const float* g4b = (const float*)d_in[9];
  const float* dw  = (const float*)d_in[10];
  const float* db  = (const float*)d_in[11];
  const float* fw  = (const float*)d_in[12];
  const float* fb  = (const float*)d_in[13];
  const float* c1w = (const float*)d_in[14];
  const float* c1b = (const float*)d_in[15];
  const float* c2w = (const float*)d_in[16];
  const float* c2b = (const float*)d_in[17];

  int N = in_sizes[0] / 3;   // 1048576
  _Float16* img = (_Float16*)d_ws;

  prep<<<(IMG_HALVES + 255)/256, 256, 0, stream>>>(
      g1w, g2w, g3w, g4w, dw, fw, c1w, c2w, img);

  // 1 block/CU (160KB LDS), 8 waves (2/SIMD), 8 batches of 64 pts per wave
  nerf_fused<<<N/4096, 512, 0, stream>>>(
      pos, dirs, img, g1b, g2b, g3b, g4b, db, fb, c1b, c2b,
      (float*)d_out, N);
}

// Round 9
// 250.564 us; speedup vs baseline: 1.1028x; 1.0985x over previous
//
#include <hip/hip_runtime.h>

// TinyNeRF fused MLP, fp16 MFMA 16x16x32, fp32 accum.
// Round-8 RESUBMIT (round-8 bench was an infra failure; kernel never ran):
// round-7 structure (ALL weights persistent in LDS, 160 KB, zero thread
// barriers after stage, in-register layer chaining via K-permuted weights;
// 512-thr block, 8 waves = 2/SIMD, 1 block/CU) with the per-wave point
// tile HALVED: st=2 (32 pts/iter, 16 iters). Evidence r3..r7: the backend
// gives the arch-VGPR side exactly half the requested wave budget
// (64 @ cap128, 128 @ cap256) regardless of launch_bounds/waves_per_eu/
// sched_barrier -> st=4's ~200-reg state spills ~290 MB/dispatch. st=2's
// ~110-reg state fits the 128 arch-VGPR allocation; per-point MFMA work
// unchanged, LDS A-frag reads double (still far under the MFMA floor).

typedef _Float16 half8 __attribute__((ext_vector_type(8)));
typedef _Float16 half2v __attribute__((ext_vector_type(2)));
typedef float f32x4 __attribute__((ext_vector_type(4)));

typedef __attribute__((address_space(1))) const unsigned int GU32;
typedef __attribute__((address_space(3))) unsigned int LU32;

#define MFMA16(A,B,C) __builtin_amdgcn_mfma_f32_16x16x32_f16(A,B,C,0,0,0)
#define SB() __builtin_amdgcn_sched_barrier(0)

#define G1A 0
#define G1B 2560
#define G2A 5120
#define G2B 13312
#define G3A 21504
#define G3B 29696
#define G4A 37888
#define G4B 46080
#define FAC 54272
#define FBC 62464
#define C1C 70656
#define C2C 80896
#define IMG_HALVES 81920

// K-axis permutation: B-slot (ks,g,jj) holds output dim
// (2ks + jj>>2)*16 + g*4 + (jj&3) of the previous layer.
__device__ __forceinline__ int permk(int s){
  int ks = s >> 5, gg = (s >> 3) & 3, jj = s & 7;
  return (2*ks + (jj >> 2))*16 + gg*4 + (jj & 3);
}

__global__ void prep(const float* __restrict__ g1w, const float* __restrict__ g2w,
                     const float* __restrict__ g3w, const float* __restrict__ g4w,
                     const float* __restrict__ dw,  const float* __restrict__ fw,
                     const float* __restrict__ c1w, const float* __restrict__ c2w,
                     _Float16* __restrict__ img) {
  int i = blockIdx.x*256 + threadIdx.x;
  if (i >= IMG_HALVES) return;
  float v = 0.f;
  size_t byteoff;
  if (i < G2A) {                       // g1: linear [2][64][40]
    int hf = (i < G1B) ? 0 : 1;
    int r = i - hf*G1B;
    int o = r / 40, s = r % 40;
    v = (s < 36) ? g1w[s*128 + hf*64 + o] : 0.f;
    byteoff = (size_t)i*2;
  } else if (i < C1C) {                // six [64][128] chunks, swz7, permk
    int ci = (i - G2A) >> 13;
    int r  = (i - G2A) & 8191;
    int o = r >> 7, s = r & 127;
    const float* W = (ci < 2) ? g2w : (ci < 4) ? g3w : (ci < 6) ? g4w : fw;
    int obase = (ci & 1)*64;
    v = W[permk(s)*128 + obase + o];
    byteoff = (size_t)(G2A + ci*8192)*2 + o*256 + ((2*s) ^ ((o & 7) << 4));
  } else if (i < C2C) {                // c1 [64][160], swz2
    int r = i - C1C;
    int o = r / 160, s = r % 160;
    if (s < 128)      v = c1w[permk(s)*64 + o];
    else if (s < 152) v = c1w[s*64 + o];
    else if (o < 16)  v = dw[permk(8*o + (s - 152))];   // d_w stash
    else              v = 0.f;
    byteoff = (size_t)C1C*2 + o*320 + ((2*s) ^ ((o & 3) << 4));
  } else {                             // c2 [16][64], swz7
    int r = i - C2C;
    int o = r >> 6, s = r & 63;
    v = (o < 3) ? c2w[permk(s)*3 + o] : 0.f;
    byteoff = (size_t)C2C*2 + o*128 + ((2*s) ^ ((o & 7) << 4));
  }
  *(_Float16*)((char*)img + byteoff) = (_Float16)v;
}

__device__ __forceinline__ half8 mk8(uint2 a, uint2 b){
  union { unsigned int u[4]; half8 h; } x;
  x.u[0]=a.x; x.u[1]=a.y; x.u[2]=b.x; x.u[3]=b.y; return x.h;
}
__device__ __forceinline__ half8 mkh8(float a,float b,float c,float d,
                                      float e,float f,float g,float h){
  half8 r; r[0]=(_Float16)a; r[1]=(_Float16)b; r[2]=(_Float16)c; r[3]=(_Float16)d;
  r[4]=(_Float16)e; r[5]=(_Float16)f; r[6]=(_Float16)g; r[7]=(_Float16)h; return r;
}
__device__ __forceinline__ uint2 pack4(float a0,float a1,float a2,float a3,bool relu){
  if (relu){ a0=fmaxf(a0,0.f); a1=fmaxf(a1,0.f); a2=fmaxf(a2,0.f); a3=fmaxf(a3,0.f); }
  union { _Float16 h[4]; uint2 u; } x;
  x.h[0]=(_Float16)a0; x.h[1]=(_Float16)a1; x.h[2]=(_Float16)a2; x.h[3]=(_Float16)a3;
  return x.u;
}

// one og-half: O=64 (og 0..3), 32 points (st=2), from persistent-LDS chunk
template<int KROWB, int KS, int PKB, bool RELU, int SWZM>
__device__ __forceinline__ void chunk32(const _Float16* buf, int lane,
                                        const float* __restrict__ bias,
                                        const half8 (&bf)[2][5], uint2 (&pk)[8][2]) {
  const int g = lane >> 4, n = lane & 15;
  const int swz = (n & SWZM) << 4;
  const char* lb = (const char*)buf + n*KROWB;
#pragma unroll
  for (int og = 0; og < 4; ++og) {
    half8 wf[KS];
#pragma unroll
    for (int ks = 0; ks < KS; ++ks)
      wf[ks] = *(const half8*)(lb + og*16*KROWB + ((ks*64 + g*16) ^ swz));
    f32x4 bv = *(const f32x4*)(bias + og*16 + g*4);
    f32x4 acc[2];
    acc[0] = bv; acc[1] = bv;
    __builtin_amdgcn_s_setprio(1);
#pragma unroll
    for (int ks = 0; ks < KS; ++ks) {
      acc[0] = MFMA16(wf[ks], bf[0][ks], acc[0]);
      acc[1] = MFMA16(wf[ks], bf[1][ks], acc[1]);
    }
    __builtin_amdgcn_s_setprio(0);
#pragma unroll
    for (int st = 0; st < 2; ++st)
      pk[PKB+og][st] = pack4(acc[st][0], acc[st][1], acc[st][2], acc[st][3], RELU);
  }
}

#define REB2() do{ \
  _Pragma("unroll") \
  for (int st_ = 0; st_ < 2; ++st_){ \
    half8 n0 = mk8(pk[0][st_], pk[1][st_]); \
    half8 n1 = mk8(pk[2][st_], pk[3][st_]); \
    half8 n2 = mk8(pk[4][st_], pk[5][st_]); \
    half8 n3 = mk8(pk[6][st_], pk[7][st_]); \
    bf[st_][0]=n0; bf[st_][1]=n1; bf[st_][2]=n2; bf[st_][3]=n3; \
  } \
}while(0)

__global__ __attribute__((amdgpu_flat_work_group_size(512, 512),
                          amdgpu_waves_per_eu(2, 2)))
void nerf_fused(
    const float* __restrict__ pos, const float* __restrict__ dirs,
    const _Float16* __restrict__ img,
    const float* __restrict__ b1, const float* __restrict__ b2,
    const float* __restrict__ b3, const float* __restrict__ b4,
    const float* __restrict__ bd, const float* __restrict__ bfl,
    const float* __restrict__ bc1, const float* __restrict__ bc2,
    float* __restrict__ out, int N) {
  __shared__ __align__(16) _Float16 W[IMG_HALVES];   // 160 KB exactly
  const int tid = threadIdx.x, wave = tid >> 6, lane = tid & 63;
  const int g = lane >> 4, n = lane & 15;

  // one-time weight stage: 512 thr x 20 x 16B = 163840 B
#pragma unroll
  for (int r = 0; r < 20; ++r)
    __builtin_amdgcn_global_load_lds((GU32*)((const char*)img + tid*16 + (size_t)r*8192),
                                     (LU32*)((char*)&W[0] + tid*16 + r*8192), 16, 0, 0);
  __syncthreads();   // the only thread barrier

  half8 bf[2][5];
  uint2 pk[8][2];
  float dv[2];                 // raw per-lane dir component (dim g), 2 regs
  const float PI = 3.14159265358979f;
  half8 z = {};

#pragma clang loop unroll(disable)
  for (int it = 0; it < 16; ++it) {
    const int pbase = blockIdx.x*4096 + wave*512 + it*32;

    // ---- encode positions directly into B-fragment form ----
#pragma unroll
    for (int st = 0; st < 2; ++st) {
      int p = pbase + st*16 + n;
      float S[3][6], C[3][6];
      const float* pp = pos + (size_t)p*3;
#pragma unroll
      for (int d = 0; d < 3; ++d) {
        float x = pp[d]*PI;
        float s = __sinf(x), c = __cosf(x);
        S[d][0]=s; C[d][0]=c;
#pragma unroll
        for (int l = 1; l < 6; ++l) {
          float s2 = 2.f*s*c, c2 = c*c - s*s;
          S[d][l]=s2; C[d][l]=c2; s=s2; c=c2;
        }
      }
      half8 e0, e1 = z;
      if (g == 0) {
        e0 = mkh8(S[0][0],S[0][1],S[0][2],S[0][3],S[0][4],S[0][5],C[0][0],C[0][1]);
        e1 = mkh8(C[2][2],C[2][3],C[2][4],C[2][5],0.f,0.f,0.f,0.f);
      } else if (g == 1) {
        e0 = mkh8(C[0][2],C[0][3],C[0][4],C[0][5],S[1][0],S[1][1],S[1][2],S[1][3]);
      } else if (g == 2) {
        e0 = mkh8(S[1][4],S[1][5],C[1][0],C[1][1],C[1][2],C[1][3],C[1][4],C[1][5]);
      } else {
        e0 = mkh8(S[2][0],S[2][1],S[2][2],S[2][3],S[2][4],S[2][5],C[2][0],C[2][1]);
      }
      bf[st][0]=e0; bf[st][1]=e1;
      // raw dir component only; encode ladder deferred to c1
      dv[st] = (g < 3) ? dirs[(size_t)p*3 + g] : 0.f;
    }
    SB();

    // ---- MLP trunk, weights LDS-resident ----
    chunk32< 80,2,0,true ,0>(&W[G1A], lane, b1,     bf, pk); SB();
    chunk32< 80,2,4,true ,0>(&W[G1B], lane, b1+64,  bf, pk); SB();
    REB2(); SB();
    chunk32<256,4,0,true ,7>(&W[G2A], lane, b2,     bf, pk); SB();
    chunk32<256,4,4,true ,7>(&W[G2B], lane, b2+64,  bf, pk); SB();
    REB2(); SB();
    chunk32<256,4,0,true ,7>(&W[G3A], lane, b3,     bf, pk); SB();
    chunk32<256,4,4,true ,7>(&W[G3B], lane, b3+64,  bf, pk); SB();
    REB2(); SB();
    chunk32<256,4,0,true ,7>(&W[G4A], lane, b4,     bf, pk); SB();
    chunk32<256,4,4,true ,7>(&W[G4B], lane, b4+64,  bf, pk); SB();
    REB2(); SB();   // bf = geo_feat fragments

    // ---- density head: dot with d_w stash (c1 pad cols), wave-local ----
    {
      half8 dwv[4];
#pragma unroll
      for (int ks = 0; ks < 4; ++ks) {
        int o = ks*4 + g;
        dwv[ks] = *(const half8*)((const char*)&W[C1C] + o*320 + (304 ^ ((o & 3) << 4)));
      }
      float dsum[2];
#pragma unroll
      for (int st = 0; st < 2; ++st) {
        float a = 0.f;
#pragma unroll
        for (int ks = 0; ks < 4; ++ks)
#pragma unroll
          for (int q = 0; q < 4; ++q) {
#if __has_builtin(__builtin_amdgcn_fdot2)
            half2v xv = {bf[st][ks][2*q], bf[st][ks][2*q+1]};
            half2v wv = {dwv[ks][2*q],    dwv[ks][2*q+1]};
            a = __builtin_amdgcn_fdot2(xv, wv, a, false);
#else
            a += (float)bf[st][ks][2*q]   * (float)dwv[ks][2*q];
            a += (float)bf[st][ks][2*q+1] * (float)dwv[ks][2*q+1];
#endif
          }
        a += __shfl_xor(a, 16);
        a += __shfl_xor(a, 32);
        dsum[st] = a;
      }
      if (g == 0) {
        float d0 = bd[0];
#pragma unroll
        for (int st = 0; st < 2; ++st) {
          float x = dsum[st] + d0;
          out[(size_t)3*N + pbase + st*16 + n] = fmaxf(x,0.f) + log1pf(__expf(-fabsf(x)));
        }
      }
    }
    SB();

    chunk32<256,4,0,false,7>(&W[FAC], lane, bfl,    bf, pk); SB();
    chunk32<256,4,4,false,7>(&W[FBC], lane, bfl+64, bf, pk); SB();
    REB2(); SB();   // bf = feature fragments

    // dir encoding, built now from the raw component
#pragma unroll
    for (int st = 0; st < 2; ++st) {
      float xx = dv[st]*PI;
      float s1 = __sinf(xx), c1 = __cosf(xx);
      float sa[4], ca[4]; sa[0]=s1; ca[0]=c1;
#pragma unroll
      for (int l = 1; l < 4; ++l) {
        float s2 = 2.f*s1*c1, c2 = c1*c1 - s1*s1;
        sa[l]=s2; ca[l]=c2; s1=s2; c1=c2;
      }
      bf[st][4] = (g < 3) ? mkh8(sa[0],sa[1],sa[2],sa[3],ca[0],ca[1],ca[2],ca[3]) : z;
    }
    SB();

    chunk32<320,5,0,true ,3>(&W[C1C], lane, bc1,    bf, pk); SB();
    // c2 input (64 dims -> 2 k-steps)
#pragma unroll
    for (int st = 0; st < 2; ++st) {
      bf[st][0] = mk8(pk[0][st], pk[1][st]);
      bf[st][1] = mk8(pk[2][st], pk[3][st]);
    }
    SB();

    // ---- rgb head ----
    {
      const char* lb = (const char*)&W[C2C] + n*128;
      const int swz = (n & 7) << 4;
      half8 wf[2];
#pragma unroll
      for (int ks = 0; ks < 2; ++ks)
        wf[ks] = *(const half8*)(lb + ((ks*64 + g*16) ^ swz));
      f32x4 a[2];
      a[0] = f32x4{0.f,0.f,0.f,0.f};
      a[1] = f32x4{0.f,0.f,0.f,0.f};
      __builtin_amdgcn_s_setprio(1);
#pragma unroll
      for (int ks = 0; ks < 2; ++ks) {
        a[0] = MFMA16(wf[ks], bf[0][ks], a[0]);
        a[1] = MFMA16(wf[ks], bf[1][ks], a[1]);
      }
      __builtin_amdgcn_s_setprio(0);
      if (g == 0) {
        float c0 = bc2[0], c1v = bc2[1], c2v = bc2[2];
#pragma unroll
        for (int st = 0; st < 2; ++st) {
          size_t p = (size_t)(pbase + st*16 + n);
          out[p*3+0] = 1.f/(1.f + __expf(-(a[st][0] + c0)));
          out[p*3+1] = 1.f/(1.f + __expf(-(a[st][1] + c1v)));
          out[p*3+2] = 1.f/(1.f + __expf(-(a[st][2] + c2v)));
        }
      }
    }
    SB();
  }
}

extern "C" void kernel_launch(void* const* d_in, const int* in_sizes, int n_in,
                              void* d_out, int out_size, void* d_ws, size_t ws_size,
                              hipStream_t stream) {
  const float* pos = (const float*)d_in[0];
  const float* dirs = (const float*)d_in[1];
  const float* g1w = (const float*)d_in[2];
  const float* g1b = (const float*)d_in[3];
  const float* g2w = (const float*)d_in[4];
  const float* g2b = (const float*)d_in[5];
  const float* g3w = (const float*)d_in[6];
  const float* g3b = (const float*)d_in[7];
  const float* g4w = (const float*)d_in[8];
  const float* g4b = (const float*)d_in[9];
  const float* dw  = (const float*)d_in[10];
  const float* db  = (const float*)d_in[11];
  const float* fw  = (const float*)d_in[12];
  const float* fb  = (const float*)d_in[13];
  const float* c1w = (const float*)d_in[14];
  const float* c1b = (const float*)d_in[15];
  const float* c2w = (const float*)d_in[16];
  const float* c2b = (const float*)d_in[17];

  int N = in_sizes[0] / 3;   // 1048576
  _Float16* img = (_Float16*)d_ws;

  prep<<<(IMG_HALVES + 255)/256, 256, 0, stream>>>(
      g1w, g2w, g3w, g4w, dw, fw, c1w, c2w, img);

  // 1 block/CU (160KB LDS), 8 waves (2/SIMD), 16 batches of 32 pts per wave
  nerf_fused<<<N/4096, 512, 0, stream>>>(
      pos, dirs, img, g1b, g2b, g3b, g4b, db, fb, c1b, c2b,
      (float*)d_out, N);
}

// Round 11
// 227.960 us; speedup vs baseline: 1.2121x; 1.0992x over previous
//
#include <hip/hip_runtime.h>

// TinyNeRF fused MLP, fp16 MFMA 16x16x32, fp32 accum.
// Round-11: round-10 (VGPR-form inline-asm MFMA, no AGPR reservation ->
// full arch-VGPR budget) + the missing MFMA->VALU hazard fences. r10's
// absmax 5e-2 failure = pack4 reading acc immediately after an opaque asm
// MFMA (no compiler-inserted wait states for inline asm). Fix: dependency-
// carried fence (3x s_nop 7 = 24 wait states, operands tied "+v") after each
// og's MFMA cluster, before any VALU read of the accumulators. Chained
// MFMA->MFMA SrcC forwarding needs no waits; all MFMA A/B sources are
// waitcnt-interlocked (ds_read/global) or >=2 instrs downstream of VALU.
// Structure otherwise identical to r9/r10: weights persistent in LDS 160KB,
// zero steady-state barriers, K-permuted in-register layer chaining,
// 512 thr (8 waves = 2/SIMD), 1 block/CU, st=2, 16 iters.

typedef _Float16 half8 __attribute__((ext_vector_type(8)));
typedef _Float16 half2v __attribute__((ext_vector_type(2)));
typedef float f32x4 __attribute__((ext_vector_type(4)));

typedef __attribute__((address_space(1))) const unsigned int GU32;
typedef __attribute__((address_space(3))) unsigned int LU32;

#define SB() __builtin_amdgcn_sched_barrier(0)

// VGPR-form MFMA via inline asm: no AGPR allocation anywhere in the kernel.
__device__ __forceinline__ f32x4 mfma16(half8 a, half8 b, f32x4 c) {
  asm("v_mfma_f32_16x16x32_f16 %0, %1, %2, %0" : "+v"(c) : "v"(a), "v"(b));
  return c;
}

// Hazard fence: >=24 wait states between the producing MFMAs and any VALU
// read of these accumulators. Dep-tied so consumers cannot be hoisted above.
__device__ __forceinline__ void fence2(f32x4 &a, f32x4 &b) {
  asm volatile("s_nop 7\n\ts_nop 7\n\ts_nop 7" : "+v"(a), "+v"(b));
}

#define G1A 0
#define G1B 2560
#define G2A 5120
#define G2B 13312
#define G3A 21504
#define G3B 29696
#define G4A 37888
#define G4B 46080
#define FAC 54272
#define FBC 62464
#define C1C 70656
#define C2C 80896
#define IMG_HALVES 81920

// K-axis permutation: B-slot (ks,g,jj) holds output dim
// (2ks + jj>>2)*16 + g*4 + (jj&3) of the previous layer.
__device__ __forceinline__ int permk(int s){
  int ks = s >> 5, gg = (s >> 3) & 3, jj = s & 7;
  return (2*ks + (jj >> 2))*16 + gg*4 + (jj & 3);
}

__global__ void prep(const float* __restrict__ g1w, const float* __restrict__ g2w,
                     const float* __restrict__ g3w, const float* __restrict__ g4w,
                     const float* __restrict__ dw,  const float* __restrict__ fw,
                     const float* __restrict__ c1w, const float* __restrict__ c2w,
                     _Float16* __restrict__ img) {
  int i = blockIdx.x*256 + threadIdx.x;
  if (i >= IMG_HALVES) return;
  float v = 0.f;
  size_t byteoff;
  if (i < G2A) {                       // g1: linear [2][64][40]
    int hf = (i < G1B) ? 0 : 1;
    int r = i - hf*G1B;
    int o = r / 40, s = r % 40;
    v = (s < 36) ? g1w[s*128 + hf*64 + o] : 0.f;
    byteoff = (size_t)i*2;
  } else if (i < C1C) {                // six [64][128] chunks, swz7, permk
    int ci = (i - G2A) >> 13;
    int r  = (i - G2A) & 8191;
    int o = r >> 7, s = r & 127;
    const float* W = (ci < 2) ? g2w : (ci < 4) ? g3w : (ci < 6) ? g4w : fw;
    int obase = (ci & 1)*64;
    v = W[permk(s)*128 + obase + o];
    byteoff = (size_t)(G2A + ci*8192)*2 + o*256 + ((2*s) ^ ((o & 7) << 4));
  } else if (i < C2C) {                // c1 [64][160], swz2
    int r = i - C1C;
    int o = r / 160, s = r % 160;
    if (s < 128)      v = c1w[permk(s)*64 + o];
    else if (s < 152) v = c1w[s*64 + o];
    else if (o < 16)  v = dw[permk(8*o + (s - 152))];   // d_w stash
    else              v = 0.f;
    byteoff = (size_t)C1C*2 + o*320 + ((2*s) ^ ((o & 3) << 4));
  } else {                             // c2 [16][64], swz7
    int r = i - C2C;
    int o = r >> 6, s = r & 63;
    v = (o < 3) ? c2w[permk(s)*3 + o] : 0.f;
    byteoff = (size_t)C2C*2 + o*128 + ((2*s) ^ ((o & 7) << 4));
  }
  *(_Float16*)((char*)img + byteoff) = (_Float16)v;
}

__device__ __forceinline__ half8 mk8(uint2 a, uint2 b){
  union { unsigned int u[4]; half8 h; } x;
  x.u[0]=a.x; x.u[1]=a.y; x.u[2]=b.x; x.u[3]=b.y; return x.h;
}
__device__ __forceinline__ half8 mkh8(float a,float b,float c,float d,
                                      float e,float f,float g,float h){
  half8 r; r[0]=(_Float16)a; r[1]=(_Float16)b; r[2]=(_Float16)c; r[3]=(_Float16)d;
  r[4]=(_Float16)e; r[5]=(_Float16)f; r[6]=(_Float16)g; r[7]=(_Float16)h; return r;
}
__device__ __forceinline__ uint2 pack4(float a0,float a1,float a2,float a3,bool relu){
  if (relu){ a0=fmaxf(a0,0.f); a1=fmaxf(a1,0.f); a2=fmaxf(a2,0.f); a3=fmaxf(a3,0.f); }
  union { _Float16 h[4]; uint2 u; } x;
  x.h[0]=(_Float16)a0; x.h[1]=(_Float16)a1; x.h[2]=(_Float16)a2; x.h[3]=(_Float16)a3;
  return x.u;
}

// one og-half: O=64 (og 0..3), 32 points (st=2), from persistent-LDS chunk
template<int KROWB, int KS, int PKB, bool RELU, int SWZM>
__device__ __forceinline__ void chunk32(const _Float16* buf, int lane,
                                        const float* __restrict__ bias,
                                        const half8 (&bf)[2][5], uint2 (&pk)[8][2]) {
  const int g = lane >> 4, n = lane & 15;
  const int swz = (n & SWZM) << 4;
  const char* lb = (const char*)buf + n*KROWB;
#pragma unroll
  for (int og = 0; og < 4; ++og) {
    half8 wf[KS];
#pragma unroll
    for (int ks = 0; ks < KS; ++ks)
      wf[ks] = *(const half8*)(lb + og*16*KROWB + ((ks*64 + g*16) ^ swz));
    f32x4 bv = *(const f32x4*)(bias + og*16 + g*4);
    f32x4 acc[2];
    acc[0] = bv; acc[1] = bv;
    __builtin_amdgcn_s_setprio(1);
#pragma unroll
    for (int ks = 0; ks < KS; ++ks) {
      acc[0] = mfma16(wf[ks], bf[0][ks], acc[0]);
      acc[1] = mfma16(wf[ks], bf[1][ks], acc[1]);
    }
    __builtin_amdgcn_s_setprio(0);
    fence2(acc[0], acc[1]);           // MFMA->VALU hazard wait states
#pragma unroll
    for (int st = 0; st < 2; ++st)
      pk[PKB+og][st] = pack4(acc[st][0], acc[st][1], acc[st][2], acc[st][3], RELU);
  }
}

#define REB2() do{ \
  _Pragma("unroll") \
  for (int st_ = 0; st_ < 2; ++st_){ \
    half8 n0 = mk8(pk[0][st_], pk[1][st_]); \
    half8 n1 = mk8(pk[2][st_], pk[3][st_]); \
    half8 n2 = mk8(pk[4][st_], pk[5][st_]); \
    half8 n3 = mk8(pk[6][st_], pk[7][st_]); \
    bf[st_][0]=n0; bf[st_][1]=n1; bf[st_][2]=n2; bf[st_][3]=n3; \
  } \
}while(0)

__global__ __attribute__((amdgpu_flat_work_group_size(512, 512),
                          amdgpu_waves_per_eu(2, 2)))
void nerf_fused(
    const float* __restrict__ pos, const float* __restrict__ dirs,
    const _Float16* __restrict__ img,
    const float* __restrict__ b1, const float* __restrict__ b2,
    const float* __restrict__ b3, const float* __restrict__ b4,
    const float* __restrict__ bd, const float* __restrict__ bfl,
    const float* __restrict__ bc1, const float* __restrict__ bc2,
    float* __restrict__ out, int N) {
  __shared__ __align__(16) _Float16 W[IMG_HALVES];   // 160 KB exactly
  const int tid = threadIdx.x, wave = tid >> 6, lane = tid & 63;
  const int g = lane >> 4, n = lane & 15;

  // one-time weight stage: 512 thr x 20 x 16B = 163840 B
#pragma unroll
  for (int r = 0; r < 20; ++r)
    __builtin_amdgcn_global_load_lds((GU32*)((const char*)img + tid*16 + (size_t)r*8192),
                                     (LU32*)((char*)&W[0] + tid*16 + r*8192), 16, 0, 0);
  __syncthreads();   // the only thread barrier

  half8 bf[2][5];
  uint2 pk[8][2];
  float dv[2];                 // raw per-lane dir component (dim g), 2 regs
  const float PI = 3.14159265358979f;
  half8 z = {};

#pragma clang loop unroll(disable)
  for (int it = 0; it < 16; ++it) {
    const int pbase = blockIdx.x*4096 + wave*512 + it*32;

    // ---- encode positions directly into B-fragment form ----
#pragma unroll
    for (int st = 0; st < 2; ++st) {
      int p = pbase + st*16 + n;
      float S[3][6], C[3][6];
      const float* pp = pos + (size_t)p*3;
#pragma unroll
      for (int d = 0; d < 3; ++d) {
        float x = pp[d]*PI;
        float s = __sinf(x), c = __cosf(x);
        S[d][0]=s; C[d][0]=c;
#pragma unroll
        for (int l = 1; l < 6; ++l) {
          float s2 = 2.f*s*c, c2 = c*c - s*s;
          S[d][l]=s2; C[d][l]=c2; s=s2; c=c2;
        }
      }
      half8 e0, e1 = z;
      if (g == 0) {
        e0 = mkh8(S[0][0],S[0][1],S[0][2],S[0][3],S[0][4],S[0][5],C[0][0],C[0][1]);
        e1 = mkh8(C[2][2],C[2][3],C[2][4],C[2][5],0.f,0.f,0.f,0.f);
      } else if (g == 1) {
        e0 = mkh8(C[0][2],C[0][3],C[0][4],C[0][5],S[1][0],S[1][1],S[1][2],S[1][3]);
      } else if (g == 2) {
        e0 = mkh8(S[1][4],S[1][5],C[1][0],C[1][1],C[1][2],C[1][3],C[1][4],C[1][5]);
      } else {
        e0 = mkh8(S[2][0],S[2][1],S[2][2],S[2][3],S[2][4],S[2][5],C[2][0],C[2][1]);
      }
      bf[st][0]=e0; bf[st][1]=e1;
      // raw dir component only; encode ladder deferred to c1
      dv[st] = (g < 3) ? dirs[(size_t)p*3 + g] : 0.f;
    }
    SB();

    // ---- MLP trunk, weights LDS-resident ----
    chunk32< 80,2,0,true ,0>(&W[G1A], lane, b1,     bf, pk); SB();
    chunk32< 80,2,4,true ,0>(&W[G1B], lane, b1+64,  bf, pk); SB();
    REB2(); SB();
    chunk32<256,4,0,true ,7>(&W[G2A], lane, b2,     bf, pk); SB();
    chunk32<256,4,4,true ,7>(&W[G2B], lane, b2+64,  bf, pk); SB();
    REB2(); SB();
    chunk32<256,4,0,true ,7>(&W[G3A], lane, b3,     bf, pk); SB();
    chunk32<256,4,4,true ,7>(&W[G3B], lane, b3+64,  bf, pk); SB();
    REB2(); SB();
    chunk32<256,4,0,true ,7>(&W[G4A], lane, b4,     bf, pk); SB();
    chunk32<256,4,4,true ,7>(&W[G4B], lane, b4+64,  bf, pk); SB();
    REB2(); SB();   // bf = geo_feat fragments

    // ---- density head: dot with d_w stash (c1 pad cols), wave-local ----
    {
      half8 dwv[4];
#pragma unroll
      for (int ks = 0; ks < 4; ++ks) {
        int o = ks*4 + g;
        dwv[ks] = *(const half8*)((const char*)&W[C1C] + o*320 + (304 ^ ((o & 3) << 4)));
      }
      float dsum[2];
#pragma unroll
      for (int st = 0; st < 2; ++st) {
        float a = 0.f;
#pragma unroll
        for (int ks = 0; ks < 4; ++ks)
#pragma unroll
          for (int q = 0; q < 4; ++q) {
#if __has_builtin(__builtin_amdgcn_fdot2)
            half2v xv = {bf[st][ks][2*q], bf[st][ks][2*q+1]};
            half2v wv = {dwv[ks][2*q],    dwv[ks][2*q+1]};
            a = __builtin_amdgcn_fdot2(xv, wv, a, false);
#else
            a += (float)bf[st][ks][2*q]   * (float)dwv[ks][2*q];
            a += (float)bf[st][ks][2*q+1] * (float)dwv[ks][2*q+1];
#endif
          }
        a += __shfl_xor(a, 16);
        a += __shfl_xor(a, 32);
        dsum[st] = a;
      }
      if (g == 0) {
        float d0 = bd[0];
#pragma unroll
        for (int st = 0; st < 2; ++st) {
          float x = dsum[st] + d0;
          out[(size_t)3*N + pbase + st*16 + n] = fmaxf(x,0.f) + log1pf(__expf(-fabsf(x)));
        }
      }
    }
    SB();

    chunk32<256,4,0,false,7>(&W[FAC], lane, bfl,    bf, pk); SB();
    chunk32<256,4,4,false,7>(&W[FBC], lane, bfl+64, bf, pk); SB();
    REB2(); SB();   // bf = feature fragments

    // dir encoding, built now from the raw component
#pragma unroll
    for (int st = 0; st < 2; ++st) {
      float xx = dv[st]*PI;
      float s1 = __sinf(xx), c1 = __cosf(xx);
      float sa[4], ca[4]; sa[0]=s1; ca[0]=c1;
#pragma unroll
      for (int l = 1; l < 4; ++l) {
        float s2 = 2.f*s1*c1, c2 = c1*c1 - s1*s1;
        sa[l]=s2; ca[l]=c2; s1=s2; c1=c2;
      }
      bf[st][4] = (g < 3) ? mkh8(sa[0],sa[1],sa[2],sa[3],ca[0],ca[1],ca[2],ca[3]) : z;
    }
    SB();

    chunk32<320,5,0,true ,3>(&W[C1C], lane, bc1,    bf, pk); SB();
    // c2 input (64 dims -> 2 k-steps)
#pragma unroll
    for (int st = 0; st < 2; ++st) {
      bf[st][0] = mk8(pk[0][st], pk[1][st]);
      bf[st][1] = mk8(pk[2][st], pk[3][st]);
    }
    SB();

    // ---- rgb head ----
    {
      const char* lb = (const char*)&W[C2C] + n*128;
      const int swz = (n & 7) << 4;
      half8 wf[2];
#pragma unroll
      for (int ks = 0; ks < 2; ++ks)
        wf[ks] = *(const half8*)(lb + ((ks*64 + g*16) ^ swz));
      f32x4 a[2];
      a[0] = f32x4{0.f,0.f,0.f,0.f};
      a[1] = f32x4{0.f,0.f,0.f,0.f};
      __builtin_amdgcn_s_setprio(1);
#pragma unroll
      for (int ks = 0; ks < 2; ++ks) {
        a[0] = mfma16(wf[ks], bf[0][ks], a[0]);
        a[1] = mfma16(wf[ks], bf[1][ks], a[1]);
      }
      __builtin_amdgcn_s_setprio(0);
      fence2(a[0], a[1]);             // MFMA->VALU hazard wait states
      if (g == 0) {
        float c0 = bc2[0], c1v = bc2[1], c2v = bc2[2];
#pragma unroll
        for (int st = 0; st < 2; ++st) {
          size_t p = (size_t)(pbase + st*16 + n);
          out[p*3+0] = 1.f/(1.f + __expf(-(a[st][0] + c0)));
          out[p*3+1] = 1.f/(1.f + __expf(-(a[st][1] + c1v)));
          out[p*3+2] = 1.f/(1.f + __expf(-(a[st][2] + c2v)));
        }
      }
    }
    SB();
  }
}

extern "C" void kernel_launch(void* const* d_in, const int* in_sizes, int n_in,
                              void* d_out, int out_size, void* d_ws, size_t ws_size,
                              hipStream_t stream) {
  const float* pos = (const float*)d_in[0];
  const float* dirs = (const float*)d_in[1];
  const float* g1w = (const float*)d_in[2];
  const float* g1b = (const float*)d_in[3];
  const float* g2w = (const float*)d_in[4];
  const float* g2b = (const float*)d_in[5];
  const float* g3w = (const float*)d_in[6];
  const float* g3b = (const float*)d_in[7];
  const float* g4w = (const float*)d_in[8];
  const float* g4b = (const float*)d_in[9];
  const float* dw  = (const float*)d_in[10];
  const float* db  = (const float*)d_in[11];
  const float* fw  = (const float*)d_in[12];
  const float* fb  = (const float*)d_in[13];
  const float* c1w = (const float*)d_in[14];
  const float* c1b = (const float*)d_in[15];
  const float* c2w = (const float*)d_in[16];
  const float* c2b = (const float*)d_in[17];

  int N = in_sizes[0] / 3;   // 1048576
  _Float16* img = (_Float16*)d_ws;

  prep<<<(IMG_HALVES + 255)/256, 256, 0, stream>>>(
      g1w, g2w, g3w, g4w, dw, fw, c1w, c2w, img);

  // 1 block/CU (160KB LDS), 8 waves (2/SIMD), 16 batches of 32 pts per wave
  nerf_fused<<<N/4096, 512, 0, stream>>>(
      pos, dirs, img, g1b, g2b, g3b, g4b, db, fb, c1b, c2b,
      (float*)d_out, N);
}

// Round 12
// 221.167 us; speedup vs baseline: 1.2493x; 1.0307x over previous
//
#include <hip/hip_runtime.h>

// TinyNeRF fused MLP, fp16 MFMA 16x16x32, fp32 accum.
// Round-12: round-11 (VGPR-form asm MFMA, no AGPR reservation, hazard
// fences, 88 VGPRs, zero spill) with the block widened to 1024 threads
// (16 waves = 4/SIMD), st=2, 8 iters/wave. r11 showed a latency-bound
// regime (MfmaUtil 27%, VALUBusy 46%, both pipes idle most of the time,
// 2 waves/SIMD). The 88-reg state now fits the 128-reg cap of 4 waves/EU
// (r3's identical attempt failed only because the MFMA builtin's AGPR
// split halved the budget to 64). Everything else identical to r11.

typedef _Float16 half8 __attribute__((ext_vector_type(8)));
typedef _Float16 half2v __attribute__((ext_vector_type(2)));
typedef float f32x4 __attribute__((ext_vector_type(4)));

typedef __attribute__((address_space(1))) const unsigned int GU32;
typedef __attribute__((address_space(3))) unsigned int LU32;

#define SB() __builtin_amdgcn_sched_barrier(0)

// VGPR-form MFMA via inline asm: no AGPR allocation anywhere in the kernel.
__device__ __forceinline__ f32x4 mfma16(half8 a, half8 b, f32x4 c) {
  asm("v_mfma_f32_16x16x32_f16 %0, %1, %2, %0" : "+v"(c) : "v"(a), "v"(b));
  return c;
}

// Hazard fence: >=24 wait states between the producing MFMAs and any VALU
// read of these accumulators. Dep-tied so consumers cannot be hoisted above.
__device__ __forceinline__ void fence2(f32x4 &a, f32x4 &b) {
  asm volatile("s_nop 7\n\ts_nop 7\n\ts_nop 7" : "+v"(a), "+v"(b));
}

#define G1A 0
#define G1B 2560
#define G2A 5120
#define G2B 13312
#define G3A 21504
#define G3B 29696
#define G4A 37888
#define G4B 46080
#define FAC 54272
#define FBC 62464
#define C1C 70656
#define C2C 80896
#define IMG_HALVES 81920

// K-axis permutation: B-slot (ks,g,jj) holds output dim
// (2ks + jj>>2)*16 + g*4 + (jj&3) of the previous layer.
__device__ __forceinline__ int permk(int s){
  int ks = s >> 5, gg = (s >> 3) & 3, jj = s & 7;
  return (2*ks + (jj >> 2))*16 + gg*4 + (jj & 3);
}

__global__ void prep(const float* __restrict__ g1w, const float* __restrict__ g2w,
                     const float* __restrict__ g3w, const float* __restrict__ g4w,
                     const float* __restrict__ dw,  const float* __restrict__ fw,
                     const float* __restrict__ c1w, const float* __restrict__ c2w,
                     _Float16* __restrict__ img) {
  int i = blockIdx.x*256 + threadIdx.x;
  if (i >= IMG_HALVES) return;
  float v = 0.f;
  size_t byteoff;
  if (i < G2A) {                       // g1: linear [2][64][40]
    int hf = (i < G1B) ? 0 : 1;
    int r = i - hf*G1B;
    int o = r / 40, s = r % 40;
    v = (s < 36) ? g1w[s*128 + hf*64 + o] : 0.f;
    byteoff = (size_t)i*2;
  } else if (i < C1C) {                // six [64][128] chunks, swz7, permk
    int ci = (i - G2A) >> 13;
    int r  = (i - G2A) & 8191;
    int o = r >> 7, s = r & 127;
    const float* W = (ci < 2) ? g2w : (ci < 4) ? g3w : (ci < 6) ? g4w : fw;
    int obase = (ci & 1)*64;
    v = W[permk(s)*128 + obase + o];
    byteoff = (size_t)(G2A + ci*8192)*2 + o*256 + ((2*s) ^ ((o & 7) << 4));
  } else if (i < C2C) {                // c1 [64][160], swz2
    int r = i - C1C;
    int o = r / 160, s = r % 160;
    if (s < 128)      v = c1w[permk(s)*64 + o];
    else if (s < 152) v = c1w[s*64 + o];
    else if (o < 16)  v = dw[permk(8*o + (s - 152))];   // d_w stash
    else              v = 0.f;
    byteoff = (size_t)C1C*2 + o*320 + ((2*s) ^ ((o & 3) << 4));
  } else {                             // c2 [16][64], swz7
    int r = i - C2C;
    int o = r >> 6, s = r & 63;
    v = (o < 3) ? c2w[permk(s)*3 + o] : 0.f;
    byteoff = (size_t)C2C*2 + o*128 + ((2*s) ^ ((o & 7) << 4));
  }
  *(_Float16*)((char*)img + byteoff) = (_Float16)v;
}

__device__ __forceinline__ half8 mk8(uint2 a, uint2 b){
  union { unsigned int u[4]; half8 h; } x;
  x.u[0]=a.x; x.u[1]=a.y; x.u[2]=b.x; x.u[3]=b.y; return x.h;
}
__device__ __forceinline__ half8 mkh8(float a,float b,float c,float d,
                                      float e,float f,float g,float h){
  half8 r; r[0]=(_Float16)a; r[1]=(_Float16)b; r[2]=(_Float16)c; r[3]=(_Float16)d;
  r[4]=(_Float16)e; r[5]=(_Float16)f; r[6]=(_Float16)g; r[7]=(_Float16)h; return r;
}
__device__ __forceinline__ uint2 pack4(float a0,float a1,float a2,float a3,bool relu){
  if (relu){ a0=fmaxf(a0,0.f); a1=fmaxf(a1,0.f); a2=fmaxf(a2,0.f); a3=fmaxf(a3,0.f); }
  union { _Float16 h[4]; uint2 u; } x;
  x.h[0]=(_Float16)a0; x.h[1]=(_Float16)a1; x.h[2]=(_Float16)a2; x.h[3]=(_Float16)a3;
  return x.u;
}

// one og-half: O=64 (og 0..3), 32 points (st=2), from persistent-LDS chunk
template<int KROWB, int KS, int PKB, bool RELU, int SWZM>
__device__ __forceinline__ void chunk32(const _Float16* buf, int lane,
                                        const float* __restrict__ bias,
                                        const half8 (&bf)[2][5], uint2 (&pk)[8][2]) {
  const int g = lane >> 4, n = lane & 15;
  const int swz = (n & SWZM) << 4;
  const char* lb = (const char*)buf + n*KROWB;
#pragma unroll
  for (int og = 0; og < 4; ++og) {
    half8 wf[KS];
#pragma unroll
    for (int ks = 0; ks < KS; ++ks)
      wf[ks] = *(const half8*)(lb + og*16*KROWB + ((ks*64 + g*16) ^ swz));
    f32x4 bv = *(const f32x4*)(bias + og*16 + g*4);
    f32x4 acc[2];
    acc[0] = bv; acc[1] = bv;
    __builtin_amdgcn_s_setprio(1);
#pragma unroll
    for (int ks = 0; ks < KS; ++ks) {
      acc[0] = mfma16(wf[ks], bf[0][ks], acc[0]);
      acc[1] = mfma16(wf[ks], bf[1][ks], acc[1]);
    }
    __builtin_amdgcn_s_setprio(0);
    fence2(acc[0], acc[1]);           // MFMA->VALU hazard wait states
#pragma unroll
    for (int st = 0; st < 2; ++st)
      pk[PKB+og][st] = pack4(acc[st][0], acc[st][1], acc[st][2], acc[st][3], RELU);
  }
}

#define REB2() do{ \
  _Pragma("unroll") \
  for (int st_ = 0; st_ < 2; ++st_){ \
    half8 n0 = mk8(pk[0][st_], pk[1][st_]); \
    half8 n1 = mk8(pk[2][st_], pk[3][st_]); \
    half8 n2 = mk8(pk[4][st_], pk[5][st_]); \
    half8 n3 = mk8(pk[6][st_], pk[7][st_]); \
    bf[st_][0]=n0; bf[st_][1]=n1; bf[st_][2]=n2; bf[st_][3]=n3; \
  } \
}while(0)

__global__ __attribute__((amdgpu_flat_work_group_size(1024, 1024),
                          amdgpu_waves_per_eu(4, 4)))
void nerf_fused(
    const float* __restrict__ pos, const float* __restrict__ dirs,
    const _Float16* __restrict__ img,
    const float* __restrict__ b1, const float* __restrict__ b2,
    const float* __restrict__ b3, const float* __restrict__ b4,
    const float* __restrict__ bd, const float* __restrict__ bfl,
    const float* __restrict__ bc1, const float* __restrict__ bc2,
    float* __restrict__ out, int N) {
  __shared__ __align__(16) _Float16 W[IMG_HALVES];   // 160 KB exactly
  const int tid = threadIdx.x, wave = tid >> 6, lane = tid & 63;
  const int g = lane >> 4, n = lane & 15;

  // one-time weight stage: 1024 thr x 10 x 16B = 163840 B
#pragma unroll
  for (int r = 0; r < 10; ++r)
    __builtin_amdgcn_global_load_lds((GU32*)((const char*)img + tid*16 + (size_t)r*16384),
                                     (LU32*)((char*)&W[0] + tid*16 + r*16384), 16, 0, 0);
  __syncthreads();   // the only thread barrier

  half8 bf[2][5];
  uint2 pk[8][2];
  float dv[2];                 // raw per-lane dir component (dim g), 2 regs
  const float PI = 3.14159265358979f;
  half8 z = {};

#pragma clang loop unroll(disable)
  for (int it = 0; it < 8; ++it) {
    const int pbase = blockIdx.x*4096 + wave*256 + it*32;

    // ---- encode positions directly into B-fragment form ----
#pragma unroll
    for (int st = 0; st < 2; ++st) {
      int p = pbase + st*16 + n;
      float S[3][6], C[3][6];
      const float* pp = pos + (size_t)p*3;
#pragma unroll
      for (int d = 0; d < 3; ++d) {
        float x = pp[d]*PI;
        float s = __sinf(x), c = __cosf(x);
        S[d][0]=s; C[d][0]=c;
#pragma unroll
        for (int l = 1; l < 6; ++l) {
          float s2 = 2.f*s*c, c2 = c*c - s*s;
          S[d][l]=s2; C[d][l]=c2; s=s2; c=c2;
        }
      }
      half8 e0, e1 = z;
      if (g == 0) {
        e0 = mkh8(S[0][0],S[0][1],S[0][2],S[0][3],S[0][4],S[0][5],C[0][0],C[0][1]);
        e1 = mkh8(C[2][2],C[2][3],C[2][4],C[2][5],0.f,0.f,0.f,0.f);
      } else if (g == 1) {
        e0 = mkh8(C[0][2],C[0][3],C[0][4],C[0][5],S[1][0],S[1][1],S[1][2],S[1][3]);
      } else if (g == 2) {
        e0 = mkh8(S[1][4],S[1][5],C[1][0],C[1][1],C[1][2],C[1][3],C[1][4],C[1][5]);
      } else {
        e0 = mkh8(S[2][0],S[2][1],S[2][2],S[2][3],S[2][4],S[2][5],C[2][0],C[2][1]);
      }
      bf[st][0]=e0; bf[st][1]=e1;
      // raw dir component only; encode ladder deferred to c1
      dv[st] = (g < 3) ? dirs[(size_t)p*3 + g] : 0.f;
    }
    SB();

    // ---- MLP trunk, weights LDS-resident ----
    chunk32< 80,2,0,true ,0>(&W[G1A], lane, b1,     bf, pk); SB();
    chunk32< 80,2,4,true ,0>(&W[G1B], lane, b1+64,  bf, pk); SB();
    REB2(); SB();
    chunk32<256,4,0,true ,7>(&W[G2A], lane, b2,     bf, pk); SB();
    chunk32<256,4,4,true ,7>(&W[G2B], lane, b2+64,  bf, pk); SB();
    REB2(); SB();
    chunk32<256,4,0,true ,7>(&W[G3A], lane, b3,     bf, pk); SB();
    chunk32<256,4,4,true ,7>(&W[G3B], lane, b3+64,  bf, pk); SB();
    REB2(); SB();
    chunk32<256,4,0,true ,7>(&W[G4A], lane, b4,     bf, pk); SB();
    chunk32<256,4,4,true ,7>(&W[G4B], lane, b4+64,  bf, pk); SB();
    REB2(); SB();   // bf = geo_feat fragments

    // ---- density head: dot with d_w stash (c1 pad cols), wave-local ----
    {
      half8 dwv[4];
#pragma unroll
      for (int ks = 0; ks < 4; ++ks) {
        int o = ks*4 + g;
        dwv[ks] = *(const half8*)((const char*)&W[C1C] + o*320 + (304 ^ ((o & 3) << 4)));
      }
      float dsum[2];
#pragma unroll
      for (int st = 0; st < 2; ++st) {
        float a = 0.f;
#pragma unroll
        for (int ks = 0; ks < 4; ++ks)
#pragma unroll
          for (int q = 0; q < 4; ++q) {
#if __has_builtin(__builtin_amdgcn_fdot2)
            half2v xv = {bf[st][ks][2*q], bf[st][ks][2*q+1]};
            half2v wv = {dwv[ks][2*q],    dwv[ks][2*q+1]};
            a = __builtin_amdgcn_fdot2(xv, wv, a, false);
#else
            a += (float)bf[st][ks][2*q]   * (float)dwv[ks][2*q];
            a += (float)bf[st][ks][2*q+1] * (float)dwv[ks][2*q+1];
#endif
          }
        a += __shfl_xor(a, 16);
        a += __shfl_xor(a, 32);
        dsum[st] = a;
      }
      if (g == 0) {
        float d0 = bd[0];
#pragma unroll
        for (int st = 0; st < 2; ++st) {
          float x = dsum[st] + d0;
          out[(size_t)3*N + pbase + st*16 + n] = fmaxf(x,0.f) + log1pf(__expf(-fabsf(x)));
        }
      }
    }
    SB();

    chunk32<256,4,0,false,7>(&W[FAC], lane, bfl,    bf, pk); SB();
    chunk32<256,4,4,false,7>(&W[FBC], lane, bfl+64, bf, pk); SB();
    REB2(); SB();   // bf = feature fragments

    // dir encoding, built now from the raw component
#pragma unroll
    for (int st = 0; st < 2; ++st) {
      float xx = dv[st]*PI;
      float s1 = __sinf(xx), c1 = __cosf(xx);
      float sa[4], ca[4]; sa[0]=s1; ca[0]=c1;
#pragma unroll
      for (int l = 1; l < 4; ++l) {
        float s2 = 2.f*s1*c1, c2 = c1*c1 - s1*s1;
        sa[l]=s2; ca[l]=c2; s1=s2; c1=c2;
      }
      bf[st][4] = (g < 3) ? mkh8(sa[0],sa[1],sa[2],sa[3],ca[0],ca[1],ca[2],ca[3]) : z;
    }
    SB();

    chunk32<320,5,0,true ,3>(&W[C1C], lane, bc1,    bf, pk); SB();
    // c2 input (64 dims -> 2 k-steps)
#pragma unroll
    for (int st = 0; st < 2; ++st) {
      bf[st][0] = mk8(pk[0][st], pk[1][st]);
      bf[st][1] = mk8(pk[2][st], pk[3][st]);
    }
    SB();

    // ---- rgb head ----
    {
      const char* lb = (const char*)&W[C2C] + n*128;
      const int swz = (n & 7) << 4;
      half8 wf[2];
#pragma unroll
      for (int ks = 0; ks < 2; ++ks)
        wf[ks] = *(const half8*)(lb + ((ks*64 + g*16) ^ swz));
      f32x4 a[2];
      a[0] = f32x4{0.f,0.f,0.f,0.f};
      a[1] = f32x4{0.f,0.f,0.f,0.f};
      __builtin_amdgcn_s_setprio(1);
#pragma unroll
      for (int ks = 0; ks < 2; ++ks) {
        a[0] = mfma16(wf[ks], bf[0][ks], a[0]);
        a[1] = mfma16(wf[ks], bf[1][ks], a[1]);
      }
      __builtin_amdgcn_s_setprio(0);
      fence2(a[0], a[1]);             // MFMA->VALU hazard wait states
      if (g == 0) {
        float c0 = bc2[0], c1v = bc2[1], c2v = bc2[2];
#pragma unroll
        for (int st = 0; st < 2; ++st) {
          size_t p = (size_t)(pbase + st*16 + n);
          out[p*3+0] = 1.f/(1.f + __expf(-(a[st][0] + c0)));
          out[p*3+1] = 1.f/(1.f + __expf(-(a[st][1] + c1v)));
          out[p*3+2] = 1.f/(1.f + __expf(-(a[st][2] + c2v)));
        }
      }
    }
    SB();
  }
}

extern "C" void kernel_launch(void* const* d_in, const int* in_sizes, int n_in,
                              void* d_out, int out_size, void* d_ws, size_t ws_size,
                              hipStream_t stream) {
  const float* pos = (const float*)d_in[0];
  const float* dirs = (const float*)d_in[1];
  const float* g1w = (const float*)d_in[2];
  const float* g1b = (const float*)d_in[3];
  const float* g2w = (const float*)d_in[4];
  const float* g2b = (const float*)d_in[5];
  const float* g3w = (const float*)d_in[6];
  const float* g3b = (const float*)d_in[7];
  const float* g4w = (const float*)d_in[8];
  const float* g4b = (const float*)d_in[9];
  const float* dw  = (const float*)d_in[10];
  const float* db  = (const float*)d_in[11];
  const float* fw  = (const float*)d_in[12];
  const float* fb  = (const float*)d_in[13];
  const float* c1w = (const float*)d_in[14];
  const float* c1b = (const float*)d_in[15];
  const float* c2w = (const float*)d_in[16];
  const float* c2b = (const float*)d_in[17];

  int N = in_sizes[0] / 3;   // 1048576
  _Float16* img = (_Float16*)d_ws;

  prep<<<(IMG_HALVES + 255)/256, 256, 0, stream>>>(
      g1w, g2w, g3w, g4w, dw, fw, c1w, c2w, img);

  // 1 block/CU (160KB LDS), 16 waves (4/SIMD), 8 batches of 32 pts per wave
  nerf_fused<<<N/4096, 1024, 0, stream>>>(
      pos, dirs, img, g1b, g2b, g3b, g4b, db, fb, c1b, c2b,
      (float*)d_out, N);
}